// Round 3
// baseline (160.011 us; speedup 1.0000x reference)
//
#include <hip/hip_runtime.h>
#include <hip/hip_bf16.h>
#include <stdint.h>

#define TT 16384
#define DD 768
#define EE 8
#define FF 469
#define FP 512
#define NCHUNK (TT / 64)

typedef __attribute__((ext_vector_type(8))) short s16x8;
typedef __attribute__((ext_vector_type(4))) float f32x4;

__device__ __forceinline__ ushort f2bf(float f) {
  uint32_t u = __builtin_bit_cast(uint32_t, f);
  u += 0x7fffu + ((u >> 16) & 1u);
  return (ushort)(u >> 16);
}

// async global->LDS, 16B per lane; LDS dest = wave-uniform base + lane*16
__device__ __forceinline__ void gload16(const void* g, void* l) {
  __builtin_amdgcn_global_load_lds((const __attribute__((address_space(1))) unsigned int*)g,
                                   (__attribute__((address_space(3))) unsigned int*)l,
                                   16, 0, 0);
}

// ---------------- fused gating (fp32) + x->bf16 conversion; NO atomics ----------------
__global__ __launch_bounds__(256) void gate_conv_kernel(
    const float* __restrict__ x, const float* __restrict__ Wg,
    const float* __restrict__ bg, int* __restrict__ eidx,
    ushort* __restrict__ xbf) {
  __shared__ float4 wgs[EE * DD / 4];  // 24 KB
  int tid = threadIdx.x;
  for (int i = tid; i < EE * DD / 4; i += 256) wgs[i] = ((const float4*)Wg)[i];
  __syncthreads();

  int t = blockIdx.x * 4 + (tid >> 6);
  int lane = tid & 63;
  const float4* xr = (const float4*)(x + (size_t)t * DD);
  float4 xv[3];
#pragma unroll
  for (int k = 0; k < 3; ++k) xv[k] = xr[lane + 64 * k];

  float acc[EE];
#pragma unroll
  for (int e = 0; e < EE; ++e) acc[e] = 0.f;
#pragma unroll
  for (int k = 0; k < 3; ++k) {
#pragma unroll
    for (int e = 0; e < EE; ++e) {
      float4 w = wgs[e * 192 + lane + 64 * k];
      acc[e] += xv[k].x * w.x + xv[k].y * w.y + xv[k].z * w.z + xv[k].w * w.w;
    }
  }

  uint2* xd = (uint2*)(xbf + (size_t)t * DD);
#pragma unroll
  for (int k = 0; k < 3; ++k) {
    union { ushort u[4]; uint2 w; } p;
    p.u[0] = f2bf(xv[k].x); p.u[1] = f2bf(xv[k].y);
    p.u[2] = f2bf(xv[k].z); p.u[3] = f2bf(xv[k].w);
    xd[lane + 64 * k] = p.w;
  }

#pragma unroll
  for (int off = 32; off; off >>= 1) {
#pragma unroll
    for (int e = 0; e < EE; ++e) acc[e] += __shfl_down(acc[e], off);
  }
  if (lane == 0) {
    float best = acc[0] + bg[0];
    int bi = 0;
#pragma unroll
    for (int e = 1; e < EE; ++e) {
      float v = acc[e] + bg[e];
      if (v > best) { best = v; bi = e; }
    }
    eidx[t] = bi;
  }
}

// ---------------- ballot histogram ----------------
__global__ void hist_kernel(const int* __restrict__ eidx, int* __restrict__ cnt) {
  int c = blockIdx.x * 4 + (threadIdx.x >> 6);
  int lane = threadIdx.x & 63;
  int v = eidx[c * 64 + lane];
#pragma unroll
  for (int e = 0; e < EE; ++e) {
    unsigned long long me = __ballot(v == e);
    if (lane == 0) cnt[e * NCHUNK + c] = __popcll(me);
  }
}

// ---------------- wave-parallel exclusive scan ----------------
__global__ void scan_kernel(const int* __restrict__ cnt, int* __restrict__ scanEx,
                            int* __restrict__ offs) {
  int e = threadIdx.x >> 6;
  int lane = threadIdx.x & 63;
  __shared__ int totals[EE];
  int carry = 0;
#pragma unroll
  for (int g = 0; g < NCHUNK / 64; ++g) {
    int v = cnt[e * NCHUNK + g * 64 + lane];
    int s = v;
#pragma unroll
    for (int d = 1; d < 64; d <<= 1) {
      int t = __shfl_up(s, d);
      if (lane >= d) s += t;
    }
    scanEx[e * NCHUNK + g * 64 + lane] = carry + s - v;
    carry += __shfl(s, 63);
  }
  if (lane == 0) totals[e] = carry;
  __syncthreads();
  if (threadIdx.x == 0) {
    int s = 0;
    for (int e2 = 0; e2 < EE; ++e2) { offs[e2] = s; s += totals[e2]; }
    offs[EE] = s;
  }
}

// ---------------- scatter via in-chunk ballot rank ----------------
__global__ void scatter2_kernel(const int* __restrict__ eidx, const int* __restrict__ offs,
                                const int* __restrict__ scanEx, int* __restrict__ perm) {
  int c = blockIdx.x * 4 + (threadIdx.x >> 6);
  int lane = threadIdx.x & 63;
  int t = c * 64 + lane;
  int v = eidx[t];
  unsigned long long mym = 0;
#pragma unroll
  for (int e = 0; e < EE; ++e) {
    unsigned long long me = __ballot(v == e);
    if (v == e) mym = me;
  }
  int rank = __popcll(mym & ((1ULL << lane) - 1ULL));
  perm[offs[v] + scanEx[v * NCHUNK + c] + rank] = t;
}

// ---------------- W1/W2 -> interleaved bf16 w12b: row 2f = W1[f], 2f+1 = W2[f] ----------------
__global__ void convw12_kernel(const float* __restrict__ W1, const float* __restrict__ W2,
                               ushort* __restrict__ w12b) {
  const int n4 = EE * 2 * FP * (DD / 4);
  for (int i = blockIdx.x * blockDim.x + threadIdx.x; i < n4; i += gridDim.x * blockDim.x) {
    int d4 = i % (DD / 4);
    int er = i / (DD / 4);
    int row = er & 1023;
    int e = er >> 10;
    int f = row >> 1;
    union { ushort u[4]; uint2 w; } p;
    if (f < FF) {
      const float* src = ((row & 1) ? W2 : W1) + ((size_t)e * FF + f) * DD;
      float4 v = ((const float4*)src)[d4];
      p.u[0] = f2bf(v.x); p.u[1] = f2bf(v.y); p.u[2] = f2bf(v.z); p.u[3] = f2bf(v.w);
    } else {
      p.w.x = 0u; p.w.y = 0u;
    }
    ((uint2*)w12b)[i] = p.w;
  }
}

__global__ void convw3_kernel(const float* __restrict__ W3, ushort* __restrict__ w3b) {
  const int n = EE * DD * FP;
  for (int i = blockIdx.x * blockDim.x + threadIdx.x; i < n; i += gridDim.x * blockDim.x) {
    int f = i % FP;
    int ed = i / FP;
    float v = (f < FF) ? W3[(size_t)ed * FF + f] : 0.f;
    w3b[i] = f2bf(v);
  }
}

// ---------------- grouped GEMM1 (m97 structure): [Ne x 768] @ w12b^T -> silu-combine -> hbf ----------------
__global__ __launch_bounds__(256) void ffn1_kernel(
    const ushort* __restrict__ xbf, const ushort* __restrict__ w12b,
    const int* __restrict__ perm, const int* __restrict__ offs,
    ushort* __restrict__ hbf) {
  int e = blockIdx.z;
  int gOff = offs[e];
  int Ne = offs[e + 1] - gOff;
  int tile0 = blockIdx.x * 128;
  if (tile0 >= Ne) return;
  int n0 = blockIdx.y * 128;  // interleaved-col base (0..1023)

  __shared__ __align__(16) short As[128 * 32];  // 8 KB, row stride 64B
  __shared__ __align__(16) short Bs[128 * 32];  // 8 KB

  int tid = threadIdx.x;
  int w = tid >> 6, lane = tid & 63;
  int lr = lane >> 2, lg = lane & 3;

  // staging: wave w stages tile rows [w*32, w*32+32), 2 insts x 16 rows, 16B/lane
  int r0 = w * 32 + lr, r1 = r0 + 16;
  int g0 = lg ^ ((r0 >> 1) & 3);  // XOR granule swizzle on the GLOBAL side
  int g1 = lg ^ ((r1 >> 1) & 3);
  int tok0 = perm[min(gOff + tile0 + r0, TT - 1)];
  int tok1 = perm[min(gOff + tile0 + r1, TT - 1)];
  const ushort* asrc0 = xbf + (size_t)tok0 * DD + g0 * 8;
  const ushort* asrc1 = xbf + (size_t)tok1 * DD + g1 * 8;
  const ushort* bsrc0 = w12b + ((size_t)(e << 10) + n0 + r0) * DD + g0 * 8;
  const ushort* bsrc1 = w12b + ((size_t)(e << 10) + n0 + r1) * DD + g1 * 8;
  short* adst0 = &As[(w * 32) * 32];
  short* adst1 = adst0 + 16 * 32;
  short* bdst0 = &Bs[(w * 32) * 32];
  short* bdst1 = bdst0 + 16 * 32;

  // compute: wave (wr,wc) owns 64x64 out; frag reads swizzled to match staging
  int wr = w >> 1, wc = w & 1;
  int lrow = lane & 15, kh = lane >> 4;
  const short* aptr[4];
  const short* bptr[4];
#pragma unroll
  for (int m = 0; m < 4; ++m) {
    int ra = wr * 64 + m * 16 + lrow;
    aptr[m] = &As[ra * 32 + (kh ^ ((ra >> 1) & 3)) * 8];
    int rb = wc * 64 + m * 16 + lrow;
    bptr[m] = &Bs[rb * 32 + (kh ^ ((rb >> 1) & 3)) * 8];
  }

  f32x4 acc[4][4];
  f32x4 zero = {0.f, 0.f, 0.f, 0.f};
#pragma unroll
  for (int m = 0; m < 4; ++m)
#pragma unroll
    for (int n = 0; n < 4; ++n) acc[m][n] = zero;

  for (int k0 = 0; k0 < DD; k0 += 32) {
    gload16(asrc0 + k0, adst0);
    gload16(asrc1 + k0, adst1);
    gload16(bsrc0 + k0, bdst0);
    gload16(bsrc1 + k0, bdst1);
    __syncthreads();
    s16x8 af[4], bfr[4];
#pragma unroll
    for (int m = 0; m < 4; ++m) af[m] = *(const s16x8*)aptr[m];
#pragma unroll
    for (int n = 0; n < 4; ++n) bfr[n] = *(const s16x8*)bptr[n];
#pragma unroll
    for (int m = 0; m < 4; ++m)
#pragma unroll
      for (int n = 0; n < 4; ++n)
        acc[m][n] = __builtin_amdgcn_mfma_f32_16x16x32_bf16(af[m], bfr[n], acc[m][n], 0, 0, 0);
    __syncthreads();
  }

  // epilogue: adjacent cols 2f,2f+1 = u_f,v_f live in adjacent lanes; shfl_xor(1) pairs them
#pragma unroll
  for (int m = 0; m < 4; ++m) {
    int rbase = tile0 + wr * 64 + m * 16 + kh * 4;
#pragma unroll
    for (int n = 0; n < 4; ++n) {
      int f = (n0 + wc * 64 + n * 16 + lrow) >> 1;
#pragma unroll
      for (int r = 0; r < 4; ++r) {
        float val = acc[m][n][r];
        float par = __shfl_xor(val, 1);
        float u = (lane & 1) ? par : val;
        float vv = (lane & 1) ? val : par;
        float h = (u / (1.f + __expf(-u))) * vv;
        int gr = rbase + r;
        if (!(lane & 1) && gr < Ne)
          hbf[(size_t)(gOff + gr) * FP + f] = f2bf(h);
      }
    }
  }
}

// ---------------- grouped GEMM2 (m97 structure): [Ne x 512] @ w3b^T -> scatter to out ----------------
__global__ __launch_bounds__(256) void ffn2_kernel(
    const ushort* __restrict__ hbf, const ushort* __restrict__ w3b,
    const int* __restrict__ perm, const int* __restrict__ offs,
    float* __restrict__ out) {
  int e = blockIdx.z;
  int gOff = offs[e];
  int Ne = offs[e + 1] - gOff;
  int tile0 = blockIdx.x * 128;
  if (tile0 >= Ne) return;
  int d0 = blockIdx.y * 128;

  __shared__ __align__(16) short As[128 * 32];
  __shared__ __align__(16) short Bs[128 * 32];

  int tid = threadIdx.x;
  int w = tid >> 6, lane = tid & 63;
  int lr = lane >> 2, lg = lane & 3;

  int r0 = w * 32 + lr, r1 = r0 + 16;
  int g0 = lg ^ ((r0 >> 1) & 3);
  int g1 = lg ^ ((r1 >> 1) & 3);
  const ushort* asrc0 = hbf + (size_t)min(gOff + tile0 + r0, TT - 1) * FP + g0 * 8;
  const ushort* asrc1 = hbf + (size_t)min(gOff + tile0 + r1, TT - 1) * FP + g1 * 8;
  const ushort* bsrc0 = w3b + ((size_t)e * DD + d0 + r0) * FP + g0 * 8;
  const ushort* bsrc1 = w3b + ((size_t)e * DD + d0 + r1) * FP + g1 * 8;
  short* adst0 = &As[(w * 32) * 32];
  short* adst1 = adst0 + 16 * 32;
  short* bdst0 = &Bs[(w * 32) * 32];
  short* bdst1 = bdst0 + 16 * 32;

  int wr = w >> 1, wc = w & 1;
  int lrow = lane & 15, kh = lane >> 4;
  const short* aptr[4];
  const short* bptr[4];
#pragma unroll
  for (int m = 0; m < 4; ++m) {
    int ra = wr * 64 + m * 16 + lrow;
    aptr[m] = &As[ra * 32 + (kh ^ ((ra >> 1) & 3)) * 8];
    int rb = wc * 64 + m * 16 + lrow;
    bptr[m] = &Bs[rb * 32 + (kh ^ ((rb >> 1) & 3)) * 8];
  }

  f32x4 acc[4][4];
  f32x4 zero = {0.f, 0.f, 0.f, 0.f};
#pragma unroll
  for (int m = 0; m < 4; ++m)
#pragma unroll
    for (int n = 0; n < 4; ++n) acc[m][n] = zero;

  for (int k0 = 0; k0 < FP; k0 += 32) {
    gload16(asrc0 + k0, adst0);
    gload16(asrc1 + k0, adst1);
    gload16(bsrc0 + k0, bdst0);
    gload16(bsrc1 + k0, bdst1);
    __syncthreads();
    s16x8 af[4], bfr[4];
#pragma unroll
    for (int m = 0; m < 4; ++m) af[m] = *(const s16x8*)aptr[m];
#pragma unroll
    for (int n = 0; n < 4; ++n) bfr[n] = *(const s16x8*)bptr[n];
#pragma unroll
    for (int m = 0; m < 4; ++m)
#pragma unroll
      for (int n = 0; n < 4; ++n)
        acc[m][n] = __builtin_amdgcn_mfma_f32_16x16x32_bf16(af[m], bfr[n], acc[m][n], 0, 0, 0);
    __syncthreads();
  }

#pragma unroll
  for (int m = 0; m < 4; ++m) {
#pragma unroll
    for (int r = 0; r < 4; ++r) {
      int gr = tile0 + wr * 64 + m * 16 + kh * 4 + r;
      if (gr < Ne) {
        int t = perm[gOff + gr];
        float* orow = out + (size_t)t * DD + d0 + wc * 64;
#pragma unroll
        for (int n = 0; n < 4; ++n) orow[n * 16 + lrow] = acc[m][n][r];
      }
    }
  }
}

extern "C" void kernel_launch(void* const* d_in, const int* in_sizes, int n_in,
                              void* d_out, int out_size, void* d_ws, size_t ws_size,
                              hipStream_t stream) {
  const float* x = (const float*)d_in[0];
  const float* Wg = (const float*)d_in[1];
  const float* bg = (const float*)d_in[2];
  const float* W1 = (const float*)d_in[3];
  const float* W2 = (const float*)d_in[4];
  const float* W3 = (const float*)d_in[5];
  float* out = (float*)d_out;

  char* ws = (char*)d_ws;
  int* eidx = (int*)ws;                            // TT ints
  int* perm = (int*)(ws + 65536);                  // TT ints
  int* offs = (int*)(ws + 131072);                 // 9 ints
  int* cnt = (int*)(ws + 131072 + 128);            // EE*NCHUNK ints
  int* scanEx = (int*)(ws + 131072 + 128 + 8192);  // EE*NCHUNK ints
  ushort* xbf = (ushort*)(ws + 262144);            // TT*DD
  ushort* w12b = xbf + (size_t)TT * DD;            // EE*1024*DD (interleaved W1/W2)
  ushort* w3b = w12b + (size_t)EE * 2 * FP * DD;   // EE*DD*FP
  ushort* hbf = w3b + (size_t)EE * DD * FP;        // TT*FP

  gate_conv_kernel<<<TT / 4, 256, 0, stream>>>(x, Wg, bg, eidx, xbf);
  convw12_kernel<<<2048, 256, 0, stream>>>(W1, W2, w12b);
  convw3_kernel<<<2048, 256, 0, stream>>>(W3, w3b);
  hist_kernel<<<NCHUNK / 4, 256, 0, stream>>>(eidx, cnt);
  scan_kernel<<<1, 512, 0, stream>>>(cnt, scanEx, offs);
  scatter2_kernel<<<NCHUNK / 4, 256, 0, stream>>>(eidx, offs, scanEx, perm);
  ffn1_kernel<<<dim3(TT / 128, 8, EE), 256, 0, stream>>>(xbf, w12b, perm, offs, hbf);
  ffn2_kernel<<<dim3(TT / 128, 6, EE), 256, 0, stream>>>(hbf, w3b, perm, offs, out);
}

// Round 4
// 119.716 us; speedup vs baseline: 1.3366x; 1.3366x over previous
//
#include <hip/hip_runtime.h>
#include <hip/hip_bf16.h>
#include <stdint.h>

#define TT 16384
#define DD 768
#define EE 8
#define FF 469
#define FP 512
#define NCHUNK (TT / 64)

typedef __attribute__((ext_vector_type(8))) short s16x8;
typedef __attribute__((ext_vector_type(4))) float f32x4;

__device__ __forceinline__ ushort f2bf(float f) {
  uint32_t u = __builtin_bit_cast(uint32_t, f);
  u += 0x7fffu + ((u >> 16) & 1u);
  return (ushort)(u >> 16);
}

__device__ __forceinline__ void gload16(const void* g, void* l) {
  __builtin_amdgcn_global_load_lds((const __attribute__((address_space(1))) unsigned int*)g,
                                   (__attribute__((address_space(3))) unsigned int*)l,
                                   16, 0, 0);
}

// ---------------- fused gating (fp32) + x->bf16 conversion; NO atomics ----------------
__global__ __launch_bounds__(256) void gate_conv_kernel(
    const float* __restrict__ x, const float* __restrict__ Wg,
    const float* __restrict__ bg, int* __restrict__ eidx,
    ushort* __restrict__ xbf) {
  __shared__ float4 wgs[EE * DD / 4];  // 24 KB
  int tid = threadIdx.x;
  for (int i = tid; i < EE * DD / 4; i += 256) wgs[i] = ((const float4*)Wg)[i];
  __syncthreads();

  int t = blockIdx.x * 4 + (tid >> 6);
  int lane = tid & 63;
  const float4* xr = (const float4*)(x + (size_t)t * DD);
  float4 xv[3];
#pragma unroll
  for (int k = 0; k < 3; ++k) xv[k] = xr[lane + 64 * k];

  float acc[EE];
#pragma unroll
  for (int e = 0; e < EE; ++e) acc[e] = 0.f;
#pragma unroll
  for (int k = 0; k < 3; ++k) {
#pragma unroll
    for (int e = 0; e < EE; ++e) {
      float4 w = wgs[e * 192 + lane + 64 * k];
      acc[e] += xv[k].x * w.x + xv[k].y * w.y + xv[k].z * w.z + xv[k].w * w.w;
    }
  }

  uint2* xd = (uint2*)(xbf + (size_t)t * DD);
#pragma unroll
  for (int k = 0; k < 3; ++k) {
    union { ushort u[4]; uint2 w; } p;
    p.u[0] = f2bf(xv[k].x); p.u[1] = f2bf(xv[k].y);
    p.u[2] = f2bf(xv[k].z); p.u[3] = f2bf(xv[k].w);
    xd[lane + 64 * k] = p.w;
  }

#pragma unroll
  for (int off = 32; off; off >>= 1) {
#pragma unroll
    for (int e = 0; e < EE; ++e) acc[e] += __shfl_down(acc[e], off);
  }
  if (lane == 0) {
    float best = acc[0] + bg[0];
    int bi = 0;
#pragma unroll
    for (int e = 1; e < EE; ++e) {
      float v = acc[e] + bg[e];
      if (v > best) { best = v; bi = e; }
    }
    eidx[t] = bi;
  }
}

// ---------------- ballot histogram ----------------
__global__ void hist_kernel(const int* __restrict__ eidx, int* __restrict__ cnt) {
  int c = blockIdx.x * 4 + (threadIdx.x >> 6);
  int lane = threadIdx.x & 63;
  int v = eidx[c * 64 + lane];
#pragma unroll
  for (int e = 0; e < EE; ++e) {
    unsigned long long me = __ballot(v == e);
    if (lane == 0) cnt[e * NCHUNK + c] = __popcll(me);
  }
}

// ---------------- wave-parallel exclusive scan ----------------
__global__ void scan_kernel(const int* __restrict__ cnt, int* __restrict__ scanEx,
                            int* __restrict__ offs) {
  int e = threadIdx.x >> 6;
  int lane = threadIdx.x & 63;
  __shared__ int totals[EE];
  int carry = 0;
#pragma unroll
  for (int g = 0; g < NCHUNK / 64; ++g) {
    int v = cnt[e * NCHUNK + g * 64 + lane];
    int s = v;
#pragma unroll
    for (int d = 1; d < 64; d <<= 1) {
      int t = __shfl_up(s, d);
      if (lane >= d) s += t;
    }
    scanEx[e * NCHUNK + g * 64 + lane] = carry + s - v;
    carry += __shfl(s, 63);
  }
  if (lane == 0) totals[e] = carry;
  __syncthreads();
  if (threadIdx.x == 0) {
    int s = 0;
    for (int e2 = 0; e2 < EE; ++e2) { offs[e2] = s; s += totals[e2]; }
    offs[EE] = s;
  }
}

// ---------------- scatter via in-chunk ballot rank ----------------
__global__ void scatter2_kernel(const int* __restrict__ eidx, const int* __restrict__ offs,
                                const int* __restrict__ scanEx, int* __restrict__ perm) {
  int c = blockIdx.x * 4 + (threadIdx.x >> 6);
  int lane = threadIdx.x & 63;
  int t = c * 64 + lane;
  int v = eidx[t];
  unsigned long long mym = 0;
#pragma unroll
  for (int e = 0; e < EE; ++e) {
    unsigned long long me = __ballot(v == e);
    if (v == e) mym = me;
  }
  int rank = __popcll(mym & ((1ULL << lane) - 1ULL));
  perm[offs[v] + scanEx[v * NCHUNK + c] + rank] = t;
}

// ---------------- W1/W2 -> interleaved bf16 w12b: row 2f = W1[f], 2f+1 = W2[f] ----------------
__global__ void convw12_kernel(const float* __restrict__ W1, const float* __restrict__ W2,
                               ushort* __restrict__ w12b) {
  const int n4 = EE * 2 * FP * (DD / 4);
  for (int i = blockIdx.x * blockDim.x + threadIdx.x; i < n4; i += gridDim.x * blockDim.x) {
    int d4 = i % (DD / 4);
    int er = i / (DD / 4);
    int row = er & 1023;
    int e = er >> 10;
    int f = row >> 1;
    union { ushort u[4]; uint2 w; } p;
    if (f < FF) {
      const float* src = ((row & 1) ? W2 : W1) + ((size_t)e * FF + f) * DD;
      float4 v = ((const float4*)src)[d4];
      p.u[0] = f2bf(v.x); p.u[1] = f2bf(v.y); p.u[2] = f2bf(v.z); p.u[3] = f2bf(v.w);
    } else {
      p.w.x = 0u; p.w.y = 0u;
    }
    ((uint2*)w12b)[i] = p.w;
  }
}

__global__ void convw3_kernel(const float* __restrict__ W3, ushort* __restrict__ w3b) {
  const int n = EE * DD * FP;
  for (int i = blockIdx.x * blockDim.x + threadIdx.x; i < n; i += gridDim.x * blockDim.x) {
    int f = i % FP;
    int ed = i / FP;
    float v = (f < FF) ? W3[(size_t)ed * FF + f] : 0.f;
    w3b[i] = f2bf(v);
  }
}

// ---------------- grouped GEMM1: dbuf + depth-1 prefetch, 1 barrier/K-step ----------------
__global__ __launch_bounds__(256) void ffn1_kernel(
    const ushort* __restrict__ xbf, const ushort* __restrict__ w12b,
    const int* __restrict__ perm, const int* __restrict__ offs,
    ushort* __restrict__ hbf) {
  // XCD-partition swizzle: nwg=8192, nwg/8=1024 = one expert slab -> XCD k owns expert k
  int bid = blockIdx.x;
  int L = (bid & 7) * 1024 + (bid >> 3);
  int xt = L & 127;
  int y = (L >> 7) & 7;
  int e = L >> 10;

  int gOff = offs[e];
  int Ne = offs[e + 1] - gOff;
  int tile0 = xt * 128;
  if (tile0 >= Ne) return;
  int n0 = y * 128;

  __shared__ __align__(16) short As[2][128 * 32];  // 2 x 8 KB
  __shared__ __align__(16) short Bs[2][128 * 32];

  int tid = threadIdx.x;
  int w = tid >> 6, lane = tid & 63;
  int lr = lane >> 2, lg = lane & 3;

  int r0 = w * 32 + lr, r1 = r0 + 16;
  int g0 = lg ^ ((r0 >> 1) & 3);
  int g1 = lg ^ ((r1 >> 1) & 3);
  int tok0 = perm[min(gOff + tile0 + r0, TT - 1)];
  int tok1 = perm[min(gOff + tile0 + r1, TT - 1)];
  const ushort* asrc0 = xbf + (size_t)tok0 * DD + g0 * 8;
  const ushort* asrc1 = xbf + (size_t)tok1 * DD + g1 * 8;
  const ushort* bsrc0 = w12b + ((size_t)(e << 10) + n0 + r0) * DD + g0 * 8;
  const ushort* bsrc1 = w12b + ((size_t)(e << 10) + n0 + r1) * DD + g1 * 8;
  int sdst0 = (w * 32) * 32;        // element offset of this wave's staging rows
  int sdst1 = sdst0 + 16 * 32;

  int wr = w >> 1, wc = w & 1;
  int lrow = lane & 15, kh = lane >> 4;
  int aoff[4], boff[4];
#pragma unroll
  for (int m = 0; m < 4; ++m) {
    int ra = wr * 64 + m * 16 + lrow;
    aoff[m] = ra * 32 + (kh ^ ((ra >> 1) & 3)) * 8;
    int rb = wc * 64 + m * 16 + lrow;
    boff[m] = rb * 32 + (kh ^ ((rb >> 1) & 3)) * 8;
  }

  f32x4 acc[4][4];
  f32x4 zero = {0.f, 0.f, 0.f, 0.f};
#pragma unroll
  for (int m = 0; m < 4; ++m)
#pragma unroll
    for (int n = 0; n < 4; ++n) acc[m][n] = zero;

  // prologue: stage tile 0 into buf 0
  gload16(asrc0, &As[0][sdst0]);
  gload16(asrc1, &As[0][sdst1]);
  gload16(bsrc0, &Bs[0][sdst0]);
  gload16(bsrc1, &Bs[0][sdst1]);
  __syncthreads();

  const int NT = DD / 32;  // 24
  for (int t = 0; t < NT; ++t) {
    int cur = t & 1;
    if (t + 1 < NT) {
      int k = (t + 1) * 32;
      gload16(asrc0 + k, &As[cur ^ 1][sdst0]);
      gload16(asrc1 + k, &As[cur ^ 1][sdst1]);
      gload16(bsrc0 + k, &Bs[cur ^ 1][sdst0]);
      gload16(bsrc1 + k, &Bs[cur ^ 1][sdst1]);
    }
    s16x8 af[4], bfr[4];
#pragma unroll
    for (int m = 0; m < 4; ++m) af[m] = *(const s16x8*)&As[cur][aoff[m]];
#pragma unroll
    for (int n = 0; n < 4; ++n) bfr[n] = *(const s16x8*)&Bs[cur][boff[n]];
#pragma unroll
    for (int m = 0; m < 4; ++m)
#pragma unroll
      for (int n = 0; n < 4; ++n)
        acc[m][n] = __builtin_amdgcn_mfma_f32_16x16x32_bf16(af[m], bfr[n], acc[m][n], 0, 0, 0);
    __syncthreads();  // drains vmcnt (next tile staged) + lgkmcnt (reads done)
  }

  // epilogue: cols 2f,2f+1 = u_f,v_f in adjacent lanes; pair via shfl_xor(1)
#pragma unroll
  for (int m = 0; m < 4; ++m) {
    int rbase = tile0 + wr * 64 + m * 16 + kh * 4;
#pragma unroll
    for (int n = 0; n < 4; ++n) {
      int f = (n0 + wc * 64 + n * 16 + lrow) >> 1;
#pragma unroll
      for (int r = 0; r < 4; ++r) {
        float val = acc[m][n][r];
        float par = __shfl_xor(val, 1);
        float u = (lane & 1) ? par : val;
        float vv = (lane & 1) ? val : par;
        float h = (u / (1.f + __expf(-u))) * vv;
        int gr = rbase + r;
        if (!(lane & 1) && gr < Ne)
          hbf[(size_t)(gOff + gr) * FP + f] = f2bf(h);
      }
    }
  }
}

// ---------------- grouped GEMM2: dbuf + depth-1 prefetch, scatter to out ----------------
__global__ __launch_bounds__(256) void ffn2_kernel(
    const ushort* __restrict__ hbf, const ushort* __restrict__ w3b,
    const int* __restrict__ perm, const int* __restrict__ offs,
    float* __restrict__ out) {
  // nwg=6144, nwg/8=768 = one expert slab (6 y x 128 x)
  int bid = blockIdx.x;
  int L = (bid & 7) * 768 + (bid >> 3);
  int xt = L & 127;
  int yq = L >> 7;
  int y = yq % 6;
  int e = yq / 6;

  int gOff = offs[e];
  int Ne = offs[e + 1] - gOff;
  int tile0 = xt * 128;
  if (tile0 >= Ne) return;
  int d0 = y * 128;

  __shared__ __align__(16) short As[2][128 * 32];
  __shared__ __align__(16) short Bs[2][128 * 32];

  int tid = threadIdx.x;
  int w = tid >> 6, lane = tid & 63;
  int lr = lane >> 2, lg = lane & 3;

  int r0 = w * 32 + lr, r1 = r0 + 16;
  int g0 = lg ^ ((r0 >> 1) & 3);
  int g1 = lg ^ ((r1 >> 1) & 3);
  const ushort* asrc0 = hbf + (size_t)min(gOff + tile0 + r0, TT - 1) * FP + g0 * 8;
  const ushort* asrc1 = hbf + (size_t)min(gOff + tile0 + r1, TT - 1) * FP + g1 * 8;
  const ushort* bsrc0 = w3b + ((size_t)e * DD + d0 + r0) * FP + g0 * 8;
  const ushort* bsrc1 = w3b + ((size_t)e * DD + d0 + r1) * FP + g1 * 8;
  int sdst0 = (w * 32) * 32;
  int sdst1 = sdst0 + 16 * 32;

  int wr = w >> 1, wc = w & 1;
  int lrow = lane & 15, kh = lane >> 4;
  int aoff[4], boff[4];
#pragma unroll
  for (int m = 0; m < 4; ++m) {
    int ra = wr * 64 + m * 16 + lrow;
    aoff[m] = ra * 32 + (kh ^ ((ra >> 1) & 3)) * 8;
    int rb = wc * 64 + m * 16 + lrow;
    boff[m] = rb * 32 + (kh ^ ((rb >> 1) & 3)) * 8;
  }

  f32x4 acc[4][4];
  f32x4 zero = {0.f, 0.f, 0.f, 0.f};
#pragma unroll
  for (int m = 0; m < 4; ++m)
#pragma unroll
    for (int n = 0; n < 4; ++n) acc[m][n] = zero;

  gload16(asrc0, &As[0][sdst0]);
  gload16(asrc1, &As[0][sdst1]);
  gload16(bsrc0, &Bs[0][sdst0]);
  gload16(bsrc1, &Bs[0][sdst1]);
  __syncthreads();

  const int NT = FP / 32;  // 16
  for (int t = 0; t < NT; ++t) {
    int cur = t & 1;
    if (t + 1 < NT) {
      int k = (t + 1) * 32;
      gload16(asrc0 + k, &As[cur ^ 1][sdst0]);
      gload16(asrc1 + k, &As[cur ^ 1][sdst1]);
      gload16(bsrc0 + k, &Bs[cur ^ 1][sdst0]);
      gload16(bsrc1 + k, &Bs[cur ^ 1][sdst1]);
    }
    s16x8 af[4], bfr[4];
#pragma unroll
    for (int m = 0; m < 4; ++m) af[m] = *(const s16x8*)&As[cur][aoff[m]];
#pragma unroll
    for (int n = 0; n < 4; ++n) bfr[n] = *(const s16x8*)&Bs[cur][boff[n]];
#pragma unroll
    for (int m = 0; m < 4; ++m)
#pragma unroll
      for (int n = 0; n < 4; ++n)
        acc[m][n] = __builtin_amdgcn_mfma_f32_16x16x32_bf16(af[m], bfr[n], acc[m][n], 0, 0, 0);
    __syncthreads();
  }

#pragma unroll
  for (int m = 0; m < 4; ++m) {
#pragma unroll
    for (int r = 0; r < 4; ++r) {
      int gr = tile0 + wr * 64 + m * 16 + kh * 4 + r;
      if (gr < Ne) {
        int t = perm[gOff + gr];
        float* orow = out + (size_t)t * DD + d0 + wc * 64;
#pragma unroll
        for (int n = 0; n < 4; ++n) orow[n * 16 + lrow] = acc[m][n][r];
      }
    }
  }
}

extern "C" void kernel_launch(void* const* d_in, const int* in_sizes, int n_in,
                              void* d_out, int out_size, void* d_ws, size_t ws_size,
                              hipStream_t stream) {
  const float* x = (const float*)d_in[0];
  const float* Wg = (const float*)d_in[1];
  const float* bg = (const float*)d_in[2];
  const float* W1 = (const float*)d_in[3];
  const float* W2 = (const float*)d_in[4];
  const float* W3 = (const float*)d_in[5];
  float* out = (float*)d_out;

  char* ws = (char*)d_ws;
  int* eidx = (int*)ws;
  int* perm = (int*)(ws + 65536);
  int* offs = (int*)(ws + 131072);
  int* cnt = (int*)(ws + 131072 + 128);
  int* scanEx = (int*)(ws + 131072 + 128 + 8192);
  ushort* xbf = (ushort*)(ws + 262144);
  ushort* w12b = xbf + (size_t)TT * DD;
  ushort* w3b = w12b + (size_t)EE * 2 * FP * DD;
  ushort* hbf = w3b + (size_t)EE * DD * FP;

  gate_conv_kernel<<<TT / 4, 256, 0, stream>>>(x, Wg, bg, eidx, xbf);
  convw12_kernel<<<2048, 256, 0, stream>>>(W1, W2, w12b);
  convw3_kernel<<<2048, 256, 0, stream>>>(W3, w3b);
  hist_kernel<<<NCHUNK / 4, 256, 0, stream>>>(eidx, cnt);
  scan_kernel<<<1, 512, 0, stream>>>(cnt, scanEx, offs);
  scatter2_kernel<<<NCHUNK / 4, 256, 0, stream>>>(eidx, offs, scanEx, perm);
  ffn1_kernel<<<8192, 256, 0, stream>>>(xbf, w12b, perm, offs, hbf);
  ffn2_kernel<<<6144, 256, 0, stream>>>(hbf, w3b, perm, offs, out);
}